// Round 3
// baseline (1303.677 us; speedup 1.0000x reference)
//
#include <hip/hip_runtime.h>

#define D 300
#define KP 320
#define NPAD 50048
#define NT64 782        // NPAD/64 row-tiles of 64
#define TPBT 4          // tiles per gemm block
#define GBX 196         // ceil(782/4)
#define NGR 256
#define NL 5
#define NC 128
#define BN_EPS 1e-5f

typedef __attribute__((ext_vector_type(8))) short bf16x8;
typedef __attribute__((ext_vector_type(4))) float f32x4;
typedef unsigned short u16;

__device__ __forceinline__ void atomAdd(float* p, float v) { unsafeAtomicAdd(p, v); }

__device__ __forceinline__ short f2bf(float f) {
    union { float f; unsigned u; } v; v.f = f;
    unsigned r = v.u + 0x7fffu + ((v.u >> 16) & 1u);   // RNE
    return (short)(r >> 16);
}
__device__ __forceinline__ float bf2f(short s) {
    union { unsigned u; float f; } v;
    v.u = ((unsigned)(u16)s) << 16;
    return v.f;
}
// HW packed f32->bf16 (RNE), 1 instr per 2 values
__device__ __forceinline__ unsigned cvtpk(float lo, float hi) {
    unsigned r;
    asm("v_cvt_pk_bf16_f32 %0, %1, %2" : "=v"(r) : "v"(lo), "v"(hi));
    return r;
}
// DPP row_shr reduce over a 16-lane row: lane with (lane&15)==15 holds the sum.
template<int C>
__device__ __forceinline__ float rs_add(float v) {
    int x = __builtin_amdgcn_update_dpp(0, __float_as_int(v), C, 0xF, 0xF, true);
    return v + __int_as_float(x);
}
__device__ __forceinline__ float red16(float v) {
    v = rs_add<0x111>(v);   // row_shr:1
    v = rs_add<0x112>(v);   // row_shr:2
    v = rs_add<0x114>(v);   // row_shr:4
    v = rs_add<0x118>(v);   // row_shr:8
    return v;
}
// async global->LDS, 16B per lane; LDS dest must be lane-linear (wave-uniform base)
__device__ __forceinline__ void gload_lds16(const u16* g, u16* l) {
    __builtin_amdgcn_global_load_lds((const __attribute__((address_space(1))) void*)g,
                                     (__attribute__((address_space(3))) void*)l, 16, 0, 0);
}

// ---------------------------------------------------------------------------
// offsets: off[g] = lower_bound(batch, g)
// ---------------------------------------------------------------------------
__global__ void offsets_kernel(const int* __restrict__ batch, int* __restrict__ off, int N) {
    int g = threadIdx.x;
    if (g > NGR) return;
    int lo = 0, hi = N;
    while (lo < hi) {
        int mid = (lo + hi) >> 1;
        if (batch[mid] < g) lo = mid + 1; else hi = mid;
    }
    off[g] = lo;
}

// ---------------------------------------------------------------------------
// CSR build: deg histogram -> hierarchical scan -> slot fill
// ---------------------------------------------------------------------------
__global__ __launch_bounds__(256)
void deg_kernel(const int* __restrict__ ei, int* __restrict__ deg, int E) {
    int e = blockIdx.x * 256 + threadIdx.x;
    if (e < E) atomicAdd(&deg[ei[E + e]], 1);
}

__global__ __launch_bounds__(256)
void degpart_kernel(const int* __restrict__ deg, int* __restrict__ part, int N) {
    int i = blockIdx.x * 256 + threadIdx.x;
    int v = (i < N) ? deg[i] : 0;
    #pragma unroll
    for (int o = 1; o < 64; o <<= 1) v += __shfl_xor(v, o);
    __shared__ int ws[4];
    if ((threadIdx.x & 63) == 0) ws[threadIdx.x >> 6] = v;
    __syncthreads();
    if (threadIdx.x == 0) part[blockIdx.x] = ws[0] + ws[1] + ws[2] + ws[3];
}

__global__ __launch_bounds__(256)
void partscan_kernel(int* __restrict__ part, int nb) {   // 1 block; nb <= 256
    __shared__ int buf[256];
    int t = threadIdx.x;
    int v = (t < nb) ? part[t] : 0;
    buf[t] = v;
    __syncthreads();
    for (int o = 1; o < 256; o <<= 1) {
        int u = (t >= o) ? buf[t - o] : 0;
        __syncthreads();
        buf[t] += u;
        __syncthreads();
    }
    if (t < nb) part[t] = (t == 0) ? 0 : buf[t - 1];   // exclusive
}

__global__ __launch_bounds__(256)
void rowptr_kernel(const int* __restrict__ deg, const int* __restrict__ part,
                   int* __restrict__ rowptr, int N, int E) {
    __shared__ int buf[256];
    int b = blockIdx.x, t = threadIdx.x;
    int i = b * 256 + t;
    int v = (i < N) ? deg[i] : 0;
    buf[t] = v;
    __syncthreads();
    for (int o = 1; o < 256; o <<= 1) {
        int u = (t >= o) ? buf[t - o] : 0;
        __syncthreads();
        buf[t] += u;
        __syncthreads();
    }
    if (i < N) rowptr[i] = part[b] + buf[t] - v;
    if (b == 0 && t == 0) rowptr[N] = E;
}

__global__ __launch_bounds__(256)
void fill_kernel(const int* __restrict__ ei, const int* __restrict__ rowptr,
                 int* __restrict__ cursor, int* __restrict__ col, int E) {
    int e = blockIdx.x * 256 + threadIdx.x;
    if (e >= E) return;
    int src = ei[e];
    int dst = ei[E + e];
    int pos = atomicAdd(&cursor[dst], 1);
    col[rowptr[dst] + pos] = src;
}

// ---------------------------------------------------------------------------
// weight convert: Wt[mat][n (320)][k (320)] = bf16(W[k][n]); pads zero
// ---------------------------------------------------------------------------
__global__ __launch_bounds__(256)
void wcvt_kernel(const float* __restrict__ W1, const float* __restrict__ W2,
                 u16* __restrict__ Wt) {
    int idx = blockIdx.x * 256 + threadIdx.x;
    if (idx >= 10 * KP * 80) return;
    int n4 = idx % 80;
    int k = (idx / 80) % KP;
    int mat = idx / (80 * KP);
    const float* Wsrc = (mat < NL) ? (W1 + (size_t)mat * D * D) : (W2 + (size_t)(mat - NL) * D * D);
    float4 w = make_float4(0.f, 0.f, 0.f, 0.f);
    if (k < D && n4 < 75) w = *(const float4*)(Wsrc + (size_t)k * D + n4 * 4);
    size_t base = ((size_t)mat * 320 + n4 * 4) * KP + k;
    Wt[base]          = (u16)f2bf(w.x);
    Wt[base + KP]     = (u16)f2bf(w.y);
    Wt[base + 2 * KP] = (u16)f2bf(w.z);
    Wt[base + 3 * KP] = (u16)f2bf(w.w);
}

// ---------------------------------------------------------------------------
// x convert: xbf[row][c] = bf16(x[row][c]), pads (c>=300, row>=N) zero
// ---------------------------------------------------------------------------
__global__ __launch_bounds__(256)
void xcvt_kernel(const float* __restrict__ x, u16* __restrict__ xbf, int N) {
    int idx = blockIdx.x * 256 + threadIdx.x;
    if (idx >= NPAD * 40) return;
    int row = idx / 40;
    int c8 = (idx - row * 40) * 8;
    short o[8];
    #pragma unroll
    for (int i = 0; i < 8; ++i) {
        int c = c8 + i;
        float f = (row < N && c < D) ? x[(size_t)row * D + c] : 0.f;
        o[i] = f2bf(f);
    }
    *(bf16x8*)(xbf + (size_t)row * KP + c8) = *(bf16x8*)o;
}

// ---------------------------------------------------------------------------
// gather with fused BN2+ReLU on source rows; edge loop unrolled x2.
// ---------------------------------------------------------------------------
template<bool APPLY>
__global__ __launch_bounds__(256)
void gather_kernel(const u16* __restrict__ H, u16* __restrict__ Z,
                   const int* __restrict__ rowptr, const int* __restrict__ col,
                   const float* __restrict__ scsh, int N) {
    int idx = blockIdx.x * 256 + threadIdx.x;
    if (idx >= N * 40) return;
    int node = idx / 40;
    int c8 = (idx - node * 40) * 8;
    float sc[8], sh[8];
    if (APPLY) {
        #pragma unroll
        for (int i = 0; i < 8; ++i) { sc[i] = scsh[c8 + i]; sh[i] = scsh[KP + c8 + i]; }
    }
    int s = rowptr[node], e = rowptr[node + 1];
    bf16x8 v = *(const bf16x8*)(H + (size_t)node * KP + c8);
    float acc[8];
    #pragma unroll
    for (int i = 0; i < 8; ++i) {
        float f = bf2f(v[i]);
        acc[i] = APPLY ? fmaxf(fmaf(f, sc[i], sh[i]), 0.f) : f;
    }
    int j = s;
    for (; j + 2 <= e; j += 2) {           // 2 row-loads in flight
        int s0 = col[j], s1 = col[j + 1];
        bf16x8 w0 = *(const bf16x8*)(H + (size_t)s0 * KP + c8);
        bf16x8 w1 = *(const bf16x8*)(H + (size_t)s1 * KP + c8);
        #pragma unroll
        for (int i = 0; i < 8; ++i) {
            float f0 = bf2f(w0[i]);
            float f1 = bf2f(w1[i]);
            acc[i] += APPLY ? fmaxf(fmaf(f0, sc[i], sh[i]), 0.f) : f0;
            acc[i] += APPLY ? fmaxf(fmaf(f1, sc[i], sh[i]), 0.f) : f1;
        }
    }
    if (j < e) {
        int s0 = col[j];
        bf16x8 w0 = *(const bf16x8*)(H + (size_t)s0 * KP + c8);
        #pragma unroll
        for (int i = 0; i < 8; ++i) {
            float f0 = bf2f(w0[i]);
            acc[i] += APPLY ? fmaxf(fmaf(f0, sc[i], sh[i]), 0.f) : f0;
        }
    }
    short o[8];
    #pragma unroll
    for (int i = 0; i < 8; ++i) o[i] = f2bf(acc[i]);
    *(bf16x8*)(Z + (size_t)node * KP + c8) = *(bf16x8*)o;
}

// ---------------------------------------------------------------------------
// pool with optional fused BN2+ReLU; one block per graph, coalesced rows.
// ---------------------------------------------------------------------------
template<bool APPLY>
__global__ __launch_bounds__(320)
void pool_kernel(const u16* __restrict__ H, const int* __restrict__ off,
                 const float* __restrict__ scsh, float* __restrict__ pooled_l) {
    __shared__ float red[8][KP];
    int t = threadIdx.x;
    int g = blockIdx.x;
    int rq = t / 40;
    int c8 = (t - rq * 40) * 8;
    float sc[8], sh[8];
    if (APPLY) {
        #pragma unroll
        for (int i = 0; i < 8; ++i) { sc[i] = scsh[c8 + i]; sh[i] = scsh[KP + c8 + i]; }
    }
    int r0 = off[g], r1 = off[g + 1];
    float a[8] = {};
    for (int r = r0 + rq; r < r1; r += 8) {
        bf16x8 v = *(const bf16x8*)(H + (size_t)r * KP + c8);
        #pragma unroll
        for (int i = 0; i < 8; ++i) {
            float f = bf2f(v[i]);
            a[i] += APPLY ? fmaxf(fmaf(f, sc[i], sh[i]), 0.f) : f;
        }
    }
    #pragma unroll
    for (int i = 0; i < 8; ++i) red[rq][c8 + i] = a[i];
    __syncthreads();
    int c = t;
    if (c < D) {
        float s = 0.f;
        #pragma unroll
        for (int j = 0; j < 8; ++j) s += red[j][c];
        pooled_l[g * D + c] = s;
    }
}

// ---------------------------------------------------------------------------
// MFMA GEMM v4: W-in-registers + A staged via global_load_lds (dbuf 2x40KB).
//   - gld_lds has no dest register -> compiler CANNOT sink the prefetch
//     (R1/R2 post-mortem: reg-prefetch was always sunk; VGPR stuck at 84).
//   - 320 threads = 5 waves; wave owns 16 cols (W frags = 40 VGPR, loaded
//     once); block covers 80-col quarter; grid (196, 4).
//   - A tile 64 rows x 320 k staged swizzled: LDS 16B-slot cc holds logical
//     slot cc ^ (row&7)  (both-sides swizzle, rule #21) -> ds_read_b128 at
//     the 8-slot floor instead of 16-way conflict.
//   - APPLY (BN1+ReLU): staged tile repacked IN LDS once per block-tile
//     (v3 redundantly repacked per-wave = 4x). Raw s_barrier (no vm drain)
//     keeps next-tile staging in flight across the repack.
//   - one full __syncthreads per tile = the T3 2-phase recipe; drain-at-
//     barrier IS the steady state since staging time >= compute time.
//   - stats: per-thread running sums; single DPP red16 + atomics at end.
// ---------------------------------------------------------------------------
template<bool APPLY>
__global__ __launch_bounds__(320, 3)
void mfma_gemm_kernel(const u16* __restrict__ Abf, const u16* __restrict__ Wt,
                      const float* __restrict__ bias, const float* __restrict__ scsh,
                      u16* __restrict__ Cbf, float* __restrict__ stats, int Nreal) {
    __shared__ u16 Ab[2][64 * 320];         // 2 x 40 KB = 80 KB
    const int tid  = threadIdx.x;
    const int wave = tid >> 6, lane = tid & 63;
    const int quad = lane >> 4, l16 = lane & 15;
    const int nW   = blockIdx.y * 80 + wave * 16;     // wave's first col
    const int tile0 = blockIdx.x * TPBT;

    // ---- W fragments -> registers (lane l16 = W row = C col; quad = k-slot)
    bf16x8 bw[10];
    {
        const u16* wp = Wt + (size_t)(nW + l16) * KP + quad * 8;
        #pragma unroll
        for (int kc = 0; kc < 10; ++kc) bw[kc] = *(const bf16x8*)(wp + kc * 32);
    }
    // bias for this thread's 4 cols
    const int c0 = nW + quad * 4;
    float bia[4];
    #pragma unroll
    for (int r = 0; r < 4; ++r) bia[r] = (c0 + r < D) ? bias[c0 + r] : 0.f;

    // scsh for the repack: this thread's fixed logical k-chunk
    float rsc[8], rsh[8];
    if (APPLY) {
        const int k0 = (((tid % 40) ^ ((tid / 40) & 7))) * 8;
        #pragma unroll
        for (int i = 0; i < 8; ++i) { rsc[i] = scsh[k0 + i]; rsh[i] = scsh[KP + k0 + i]; }
    }

    // ---- stage one 64x320 tile (2560 16B chunks, 8 per thread), swizzled src
    auto stage = [&](int buf, int tile) {
        const size_t rowb = (size_t)tile * 64;
        #pragma unroll
        for (int i = 0; i < 8; ++i) {
            int chunk = i * 320 + tid;
            int r  = chunk / 40;
            int cc = chunk - r * 40;
            int off = (cc * 16) ^ ((r & 7) << 4);          // swizzled byte off in row
            gload_lds16(Abf + (rowb + r) * KP + (off >> 1), &Ab[buf][chunk * 8]);
        }
    };

    stage(0, tile0);
    __syncthreads();                       // drains W loads + first stage

    float sl[4] = {0.f, 0.f, 0.f, 0.f}, ql[4] = {0.f, 0.f, 0.f, 0.f};
    int cur = 0;

    for (int i = 0; i < TPBT; ++i) {
        const int tile = tile0 + i;
        if (tile >= NT64) break;
        if (i + 1 < TPBT && tile + 1 < NT64) stage(cur ^ 1, tile + 1);

        if (APPLY) {
            // repack staged tile in place: h = relu(z*sc + sh), once per element
            #pragma unroll
            for (int u = 0; u < 8; ++u) {
                const int chunk = u * 320 + tid;
                bf16x8 v = *(const bf16x8*)&Ab[cur][chunk * 8];
                float f[8];
                #pragma unroll
                for (int j = 0; j < 8; ++j)
                    f[j] = fmaxf(fmaf(bf2f(v[j]), rsc[j], rsh[j]), 0.f);
                union { unsigned w[4]; bf16x8 v; } o;
                o.w[0] = cvtpk(f[0], f[1]);
                o.w[1] = cvtpk(f[2], f[3]);
                o.w[2] = cvtpk(f[4], f[5]);
                o.w[3] = cvtpk(f[6], f[7]);
                *(bf16x8*)&Ab[cur][chunk * 8] = o.v;
            }
            asm volatile("s_waitcnt lgkmcnt(0)" ::: "memory");  // my LDS writes done
            __builtin_amdgcn_sched_barrier(0);
            __builtin_amdgcn_s_barrier();   // raw barrier: staging stays in flight
        }

        f32x4 acc[4] = {};
        #pragma unroll
        for (int kc = 0; kc < 10; ++kc) {
            #pragma unroll
            for (int rg = 0; rg < 4; ++rg) {
                const int row = rg * 16 + l16;
                const int off = (kc * 64 + quad * 16) ^ ((l16 & 7) << 4);
                bf16x8 af = *(const bf16x8*)&Ab[cur][row * 320 + (off >> 1)];
                acc[rg] = __builtin_amdgcn_mfma_f32_16x16x32_bf16(bw[kc], af, acc[rg], 0, 0, 0);
            }
        }

        // epilogue: thread owns rows {tile*64 + rg*16 + l16}, cols c0..c0+3
        const int rowb = tile * 64;
        u16* cr = Cbf + (size_t)(rowb + l16) * KP + c0;
        #pragma unroll
        for (int rg = 0; rg < 4; ++rg) {
            float v[4];
            #pragma unroll
            for (int r = 0; r < 4; ++r) v[r] = acc[rg][r] + bia[r];
            uint2 w;
            w.x = cvtpk(v[0], v[1]);
            w.y = cvtpk(v[2], v[3]);
            *(uint2*)(cr + (size_t)(rg * 16) * KP) = w;
            const bool ok = (rowb + rg * 16 + l16) < Nreal;
            #pragma unroll
            for (int r = 0; r < 4; ++r) {
                float s0 = ok ? v[r] : 0.f;
                sl[r] += s0;
                ql[r] = fmaf(s0, s0, ql[r]);
            }
        }
        __syncthreads();                   // staging done + all reads of cur done
        cur ^= 1;
    }

    // ---- column stats: reduce over the 16 row-lanes, atomics from lane 15
    #pragma unroll
    for (int r = 0; r < 4; ++r) {
        float sv = red16(sl[r]);
        float qv = red16(ql[r]);
        if (l16 == 15 && c0 + r < D) {
            atomAdd(&stats[c0 + r], sv);
            atomAdd(&stats[KP + c0 + r], qv);
        }
    }
}

// ---------------------------------------------------------------------------
// BN finalize; self-zeroes stats for the next GEMM
// ---------------------------------------------------------------------------
__global__ void bnfin_kernel(float* __restrict__ sums, const float* __restrict__ g,
                             const float* __restrict__ be, float* __restrict__ scsh, float invN) {
    int c = threadIdx.x;
    if (c >= D) return;
    float mu = sums[c] * invN;
    float var = sums[KP + c] * invN - mu * mu;
    float s = g[c] / sqrtf(var + BN_EPS);
    scsh[c] = s;
    scsh[KP + c] = fmaf(-mu, s, be[c]);
    sums[c] = 0.f;
    sums[KP + c] = 0.f;
}

// ---------------------------------------------------------------------------
// readout
// ---------------------------------------------------------------------------
__global__ __launch_bounds__(128)
void bias_init_kernel(const float* __restrict__ fcb, float* __restrict__ out) {
    int i = blockIdx.x * 128 + threadIdx.x;
    if (i >= NGR * NC) return;
    int c = i & (NC - 1);
    float s = 0.f;
    for (int l = 0; l <= NL; ++l) s += fcb[l * NC + c];
    out[i] = s;
}

__global__ __launch_bounds__(128)
void readout_kernel(const float* __restrict__ pooled, const int* __restrict__ off,
                    const float* __restrict__ fcW, float* __restrict__ out) {
    __shared__ float sp[4][D];
    int c = threadIdx.x;
    int l = blockIdx.y;
    int g0 = blockIdx.x * 4;
    for (int i = c; i < 4 * D; i += 128) {
        int gg = i / D, k = i - gg * D;
        sp[gg][k] = pooled[((size_t)l * NGR + g0 + gg) * D + k];
    }
    __syncthreads();
    float acc[4] = {0.f, 0.f, 0.f, 0.f};
    for (int k = 0; k < D; ++k) {
        float w = fcW[((size_t)l * D + k) * NC + c];
        #pragma unroll
        for (int gg = 0; gg < 4; ++gg) acc[gg] = fmaf(sp[gg][k], w, acc[gg]);
    }
    #pragma unroll
    for (int gg = 0; gg < 4; ++gg) {
        int g = g0 + gg;
        float inv = 1.0f / fmaxf((float)(off[g + 1] - off[g]), 1.0f);
        atomAdd(&out[g * NC + c], acc[gg] * inv);
    }
}

// ---------------------------------------------------------------------------
extern "C" void kernel_launch(void* const* d_in, const int* in_sizes, int n_in,
                              void* d_out, int out_size, void* d_ws, size_t ws_size,
                              hipStream_t stream) {
    const float* x       = (const float*)d_in[0];
    const int*   ei      = (const int*)d_in[1];
    const int*   batch   = (const int*)d_in[2];
    const float* W1  = (const float*)d_in[3];
    const float* b1  = (const float*)d_in[4];
    const float* g1  = (const float*)d_in[5];
    const float* be1 = (const float*)d_in[6];
    const float* W2  = (const float*)d_in[7];
    const float* b2  = (const float*)d_in[8];
    const float* bng = (const float*)d_in[9];
    const float* bnb = (const float*)d_in[10];
    const float* fcW = (const float*)d_in[11];
    const float* fcb = (const float*)d_in[12];
    float* out = (float*)d_out;

    const int N = in_sizes[0] / D;   // 50000
    const int E = in_sizes[1] / 2;   // 400000
    const int nb = (N + 255) / 256;  // scan blocks

    u16* xbf  = (u16*)d_ws;                      // NPAD*KP
    u16* bufA = xbf + (size_t)NPAD * KP;         // NPAD*KP
    u16* bufB = bufA + (size_t)NPAD * KP;        // NPAD*KP
    u16* Wt   = bufB + (size_t)NPAD * KP;        // 10*320*KP
    float* pooled = (float*)(Wt + (size_t)10 * 320 * KP);    // 6*NGR*D
    float* stats  = pooled + (size_t)(NL + 1) * NGR * D;     // 2*KP
    float* sc1    = stats + 2 * KP;                          // 2*KP
    float* sc2    = sc1 + 2 * KP;                            // 2*KP
    int*   off    = (int*)(sc2 + 2 * KP);                    // NGR+1
    int*   rowptr = off + NGR + 1;                           // N+1
    int*   cursor = rowptr + N + 1;                          // N
    int*   col    = cursor + N;                              // E
    int*   part   = col + E;                                 // 256

    hipMemsetAsync(stats, 0, 6 * KP * sizeof(float), stream);   // stats + sc1 + sc2 pads
    offsets_kernel<<<1, 320, 0, stream>>>(batch, off, N);
    bias_init_kernel<<<(NGR * NC + 127) / 128, 128, 0, stream>>>(fcb, out);

    // ---- CSR build (once) ----
    hipMemsetAsync(cursor, 0, N * sizeof(int), stream);
    deg_kernel<<<(E + 255) / 256, 256, 0, stream>>>(ei, cursor, E);
    degpart_kernel<<<nb, 256, 0, stream>>>(cursor, part, N);
    partscan_kernel<<<1, 256, 0, stream>>>(part, nb);
    rowptr_kernel<<<nb, 256, 0, stream>>>(cursor, part, rowptr, N, E);
    hipMemsetAsync(cursor, 0, N * sizeof(int), stream);
    fill_kernel<<<(E + 255) / 256, 256, 0, stream>>>(ei, rowptr, cursor, col, E);

    // ---- precompute bf16 weights + input ----
    wcvt_kernel<<<(10 * KP * 80 + 255) / 256, 256, 0, stream>>>(W1, W2, Wt);
    xcvt_kernel<<<(NPAD * 40 + 255) / 256, 256, 0, stream>>>(x, xbf, N);

    const dim3 gemm_grid(GBX, 4);
    const int nd40 = N * 40;
    float invN = 1.0f / (float)N;
    const size_t WtM = (size_t)320 * KP;

    // pooled[0] = sum of raw x rows per graph
    pool_kernel<false><<<NGR, 320, 0, stream>>>(xbf, off, sc2, pooled);

    u16* g = bufA;
    u16* t = bufB;
    const u16* src = xbf;
    for (int l = 0; l < NL; ++l) {
        // gather (+BN2/ReLU of prev layer for l>0): src -> g
        if (l == 0)
            gather_kernel<false><<<(nd40 + 255) / 256, 256, 0, stream>>>(src, g, rowptr, col, sc2, N);
        else
            gather_kernel<true><<<(nd40 + 255) / 256, 256, 0, stream>>>(src, g, rowptr, col, sc2, N);
        // GEMM1 (+stats): g @ W1 -> t      (stats zeroed by prior bnfin)
        mfma_gemm_kernel<false><<<gemm_grid, 320, 0, stream>>>(
            g, Wt + (size_t)l * WtM, b1 + l * D, sc1, t, stats, N);
        bnfin_kernel<<<1, 320, 0, stream>>>(stats, g1 + l * D, be1 + l * D, sc1, invN);
        // GEMM2 (BN1+ReLU applied to staged A in LDS, +stats): t @ W2 -> g
        mfma_gemm_kernel<true><<<gemm_grid, 320, 0, stream>>>(
            t, Wt + (size_t)(NL + l) * WtM, b2 + l * D, sc1, g, stats, N);
        bnfin_kernel<<<1, 320, 0, stream>>>(stats, bng + l * D, bnb + l * D, sc2, invN);
        // pooled[l+1] = per-graph sum of relu(bn2(z_l)) via on-the-fly apply
        pool_kernel<true><<<NGR, 320, 0, stream>>>(g, off, sc2, pooled + (size_t)(l + 1) * NGR * D);
        src = g;
        u16* tmp = g; g = t; t = tmp;
    }
    readout_kernel<<<dim3(NGR / 4, NL + 1), 128, 0, stream>>>(pooled, off, fcW, out);
}